// Round 8
// baseline (870.395 us; speedup 1.0000x reference)
//
#include <hip/hip_runtime.h>

// SVF scaling-and-squaring: 16 steps of warp <- warp + sample(warp, id + warp)
// Brick layout: float index of voxel (x,y,z) =
//   ((((z>>1)*80 + (y>>1))*160 + x)*4 + ((z&1)*2 + (y&1))) * 3
// Position math: gx = x + 80*w (algebraic simplification of the reference
// chain; error ~6e-5 voxels). fp32 intermediates are mandatory: per-step
// errors amplify ~2x per remaining step (observed absmax 0.0156->0.0234
// from even the position simplification).
// Each thread processes the y-adjacent voxel PAIR of a brick unit:
// doubles gather MLP (latency-bound early steps), own load/store becomes
// 6 contiguous floats.

constexpr int S   = 160;
constexpr int VOX = S * S * S;        // 4,096,000
constexpr int THREADS = 256;
constexpr int CBLOCKS = VOX / THREADS;       // 16000 (copy kernel)
constexpr int PBLOCKS = (VOX / 2) / THREADS; // 8000  (pair kernels)
constexpr int NXCD   = 8;
constexpr int CCHUNK = CBLOCKS / NXCD;  // 2000
constexpr int PCHUNK = PBLOCKS / NXCD;  // 1000

__device__ __forceinline__ float idcoord(int u) {
    // matches jnp: (2.0*arange + 1.0)/160.0 - 1.0 in fp32
    return (2.0f * (float)u + 1.0f) / 160.0f - 1.0f;
}

__device__ __forceinline__ float4 ld4u(const float* p) { float4 r; __builtin_memcpy(&r, p, 16); return r; }
__device__ __forceinline__ float2 ld2u(const float* p) { float2 r; __builtin_memcpy(&r, p, 8);  return r; }

// brick float-index of voxel (x,y,z)
__device__ __forceinline__ int brickf(int x, int y, int z) {
    return ((((z >> 1) * 80 + (y >> 1)) * S + x) * 4 + ((z & 1) * 2 + (y & 1))) * 3;
}

// Copy: v planar -> brick, scaled by 2^-16 (exact). 32x4x2 tile per block.
__global__ __launch_bounds__(THREADS) void svf_copy(const float* __restrict__ src,
                                                    float* __restrict__ dst,
                                                    float scale) {
    const int b   = blockIdx.x;
    const int blk = (b & (NXCD - 1)) * CCHUNK + (b >> 3);
    const int bx = blk % 5;
    const int by = (blk / 5) % 40;
    const int bz = blk / 200;

    const int tid = threadIdx.x;
    const int x = bx * 32 + (tid & 31);
    const int y = by * 4 + ((tid >> 5) & 3);
    const int z = bz * 2 + (tid >> 7);

    const int idx = (z * S + y) * S + x;
    const float w0 = src[idx] * scale;
    const float w1 = src[idx + VOX] * scale;
    const float w2 = src[idx + 2 * VOX] * scale;

    const int f = brickf(x, y, z);
    float2 st = make_float2(w0, w1);
    __builtin_memcpy(dst + f, &st, 8);
    dst[f + 2] = w2;
}

// One voxel's gather + combine. Returns n = w + sample(src, pos(w)).
__device__ __forceinline__ void sample_one(const float* __restrict__ src,
                                           int x, int y, int z,
                                           float w0, float w1, float w2,
                                           float& n0, float& n1, float& n2) {
    float gx = fminf(fmaxf(fmaf(80.0f, w0, (float)x), 0.0f), 159.0f);
    float gy = fminf(fmaxf(fmaf(80.0f, w1, (float)y), 0.0f), 159.0f);
    float gz = fminf(fmaxf(fmaf(80.0f, w2, (float)z), 0.0f), 159.0f);

    const float x0f = floorf(gx), y0f = floorf(gy), z0f = floorf(gz);
    const float fx = gx - x0f, fy = gy - y0f, fz = gz - z0f;
    const int x0 = (int)x0f, y0 = (int)y0f, z0 = (int)z0f;
    const int x1 = min(x0 + 1, S - 1);
    const int y1 = min(y0 + 1, S - 1);
    const int z1 = min(z0 + 1, S - 1);
    const float ofx = 1.0f - fx, ofy = 1.0f - fy, ofz = 1.0f - fz;

    const int Y0 = (y0 >> 1) * 1920 + (y0 & 1) * 3;   // 1920 = 160*4*3
    const int Y1 = (y1 >> 1) * 1920 + (y1 & 1) * 3;
    const int Z0 = (z0 >> 1) * 153600 + (z0 & 1) * 6; // 153600 = 80*160*4*3
    const int Z1 = (z1 >> 1) * 153600 + (z1 & 1) * 6;
    const int rb4[4] = { Z0 + Y0, Z0 + Y1, Z1 + Y0, Z1 + Y1 };

    const int xo0 = x0 * 12, xo1 = x1 * 12;
    float g0[4], g1[4], g2[4];
    #pragma unroll
    for (int q = 0; q < 4; ++q) {
        float4 A = ld4u(src + rb4[q] + xo0);
        float4 B = ld4u(src + rb4[q] + xo1);
        g0[q] = A.x * ofx + B.x * fx;
        g1[q] = A.y * ofx + B.y * fx;
        g2[q] = A.z * ofx + B.z * fx;
    }
    float r0 = (g0[0] * ofy + g0[1] * fy) * ofz + (g0[2] * ofy + g0[3] * fy) * fz;
    float r1 = (g1[0] * ofy + g1[1] * fy) * ofz + (g1[2] * ofy + g1[3] * fy) * fz;
    float r2 = (g2[0] * ofy + g2[1] * fy) * ofz + (g2[2] * ofy + g2[3] * fy) * fz;

    n0 = w0 + r0;
    n1 = w1 + r1;
    n2 = w2 + r2;
}

// MODE 1: brick -> brick (steps 1..15).  MODE 2: brick -> planar + identity.
// One thread = one brick unit's y-pair (ly=0,1) at fixed (x, lz).
template <int MODE>
__global__ __launch_bounds__(THREADS) void svf_step(const float* __restrict__ src,
                                                    float* __restrict__ dst) {
    const int b   = blockIdx.x;
    const int blk = (b & (NXCD - 1)) * PCHUNK + (b >> 3);
    const int p   = blk * THREADS + threadIdx.x;   // pair id

    const int lz   = p & 1;
    const int unit = p >> 1;
    const int x  = unit % S;
    const int t  = unit / S;        // zb*80 + yb
    const int yb = t % 80;
    const int zb = t / 80;
    const int yA = yb * 2;          // voxel A: ly=0, voxel B: ly=1
    const int z  = zb * 2 + lz;

    const int fo = unit * 12 + lz * 6;   // own base: 6 contiguous floats
    float4 o4 = ld4u(src + fo);
    float2 o2 = ld2u(src + fo + 4);
    const float a0 = o4.x, a1 = o4.y, a2 = o4.z;       // voxel A warp
    const float b0 = o4.w, b1 = o2.x, b2 = o2.y;       // voxel B warp

    float nA0, nA1, nA2, nB0, nB1, nB2;
    sample_one(src, x, yA,     z, a0, a1, a2, nA0, nA1, nA2);
    sample_one(src, x, yA + 1, z, b0, b1, b2, nB0, nB1, nB2);

    if (MODE == 2) {
        const int pidx = (z * S + yA) * S + x;
        const float icx = idcoord(x), icz = idcoord(z);
        dst[pidx]               = icx + nA0;
        dst[pidx + VOX]         = idcoord(yA) + nA1;
        dst[pidx + 2 * VOX]     = icz + nA2;
        dst[pidx + S]           = icx + nB0;
        dst[pidx + S + VOX]     = idcoord(yA + 1) + nB1;
        dst[pidx + S + 2 * VOX] = icz + nB2;
    } else {
        float4 s4 = make_float4(nA0, nA1, nA2, nB0);
        float2 s2 = make_float2(nB1, nB2);
        __builtin_memcpy(dst + fo, &s4, 16);
        __builtin_memcpy(dst + fo + 4, &s2, 8);
    }
}

extern "C" void kernel_launch(void* const* d_in, const int* in_sizes, int n_in,
                              void* d_out, int out_size, void* d_ws, size_t ws_size,
                              hipStream_t stream) {
    // in[0] = identity_grid (recomputed analytically), in[1] = v
    const float* v = (const float*)d_in[1];
    float* out = (float*)d_out;
    float* ws  = (float*)d_ws;   // 3*160^3*4 = 49.15 MB used

    const float s = 1.0f / 65536.0f;  // 2^-16, exact

    // init: v (planar, scaled) -> out used as brick scratch
    svf_copy<<<CBLOCKS, THREADS, 0, stream>>>(v, out, s);
    // steps 1..15: ping-pong; odd step -> ws, even step -> out.
    // step 15 lands in ws, so the final pass reads ws and writes out (planar).
    for (int k = 1; k <= 15; ++k) {
        if (k & 1)
            svf_step<1><<<PBLOCKS, THREADS, 0, stream>>>(out, ws);
        else
            svf_step<1><<<PBLOCKS, THREADS, 0, stream>>>(ws, out);
    }
    // step 16: ws (brick) -> d_out planar + identity
    svf_step<2><<<PBLOCKS, THREADS, 0, stream>>>(ws, out);
}

// Round 9
// 603.491 us; speedup vs baseline: 1.4423x; 1.4423x over previous
//
#include <hip/hip_runtime.h>

// SVF scaling-and-squaring: 16 steps of warp <- warp + sample(warp, id + warp)
//
// Phase A (steps 1..8): displacement |80*w| < 1 voxel (rigorous bound
//   |w_k| <= 2^k max|v| / 2^16, needs max|v| < 6.4; ~5.5 for this input).
//   Planar layout; each block stages a 34x10x6 halo tile in LDS and serves
//   all 8 trilinear corners from LDS. Border clamp is free: clamped staging
//   duplicates border rows exactly where min(c+1,159) would read.
// Phase B (steps 9..15 + final): y/z-paired brick layout, global gather
//   (round-7 proven kernels, one voxel per thread -- the round-8 pair
//   experiment showed 2 chains/thread serializes under VGPR pressure).

constexpr int S   = 160;
constexpr int VOX = S * S * S;        // 4,096,000
constexpr int THREADS = 256;
constexpr int BBLOCKS = VOX / THREADS;   // 16000 (brick + copy kernels)
constexpr int NXCD  = 8;
constexpr int BCHUNK = BBLOCKS / NXCD;   // 2000

// LDS kernel tiling
constexpr int LBLOCKS = 4000;            // 5 x 20 x 40 tiles of 32x8x4
constexpr int LCHUNK  = LBLOCKS / NXCD;  // 500
constexpr int LS_X = 34, LS_Y = 10, LS_Z = 6;
constexpr int LREG  = LS_X * LS_Y * LS_Z;   // 2040 staged voxels
constexpr int LFLT  = 3 * LREG;             // 6120 floats = 24.5 KB

__device__ __forceinline__ float idcoord(int u) {
    // matches jnp: (2.0*arange + 1.0)/160.0 - 1.0 in fp32
    return (2.0f * (float)u + 1.0f) / 160.0f - 1.0f;
}

__device__ __forceinline__ float4 ld4u(const float* p) { float4 r; __builtin_memcpy(&r, p, 16); return r; }

// brick float-index of voxel (x,y,z)
__device__ __forceinline__ int brickf(int x, int y, int z) {
    return ((((z >> 1) * 80 + (y >> 1)) * S + x) * 4 + ((z & 1) * 2 + (y & 1))) * 3;
}

// ---------- Phase A: planar LDS-gather step (steps 1..8) ----------
__global__ __launch_bounds__(THREADS) void svf_lds(const float* __restrict__ src,
                                                   float* __restrict__ dst,
                                                   float scale) {
    __shared__ float sm[LFLT];

    const int b   = blockIdx.x;
    const int blk = (b & (NXCD - 1)) * LCHUNK + (b >> 3);
    const int bx = blk % 5;
    const int by = (blk / 5) % 20;
    const int bz = blk / 100;

    const int XS = bx * 32 - 1;   // staged-region origin (may be -1)
    const int YS = by * 8 - 1;
    const int ZS = bz * 4 - 1;

    const int tid = threadIdx.x;

    // stage 34x10x6 x 3ch, clamped at borders, scaled (scale=1 for steps 2..8)
    for (int f = tid; f < LFLT; f += THREADS) {
        int c  = f / LREG;
        int r  = f - c * LREG;
        int lz = r / (LS_Y * LS_X);
        int r2 = r - lz * (LS_Y * LS_X);
        int ly = r2 / LS_X;
        int lx = r2 - ly * LS_X;
        int X = min(max(XS + lx, 0), S - 1);
        int Y = min(max(YS + ly, 0), S - 1);
        int Z = min(max(ZS + lz, 0), S - 1);
        sm[f] = src[c * VOX + (Z * S + Y) * S + X] * scale;
    }
    __syncthreads();

    const int lxi = tid & 31;
    const int tyi = tid >> 5;          // [0,8)
    const int x = XS + 1 + lxi;
    const int y = YS + 1 + tyi;

    #pragma unroll
    for (int q = 0; q < 4; ++q) {
        const int z = ZS + 1 + q;

        // own value from LDS
        const int lown = ((q + 1) * LS_Y + (tyi + 1)) * LS_X + (lxi + 1);
        const float w0 = sm[lown];
        const float w1 = sm[lown + LREG];
        const float w2 = sm[lown + 2 * LREG];

        float gx = fminf(fmaxf(fmaf(80.0f, w0, (float)x), 0.0f), 159.0f);
        float gy = fminf(fmaxf(fmaf(80.0f, w1, (float)y), 0.0f), 159.0f);
        float gz = fminf(fmaxf(fmaf(80.0f, w2, (float)z), 0.0f), 159.0f);

        const float x0f = floorf(gx), y0f = floorf(gy), z0f = floorf(gz);
        const float fx = gx - x0f, fy = gy - y0f, fz = gz - z0f;
        const float ofx = 1.0f - fx, ofy = 1.0f - fy, ofz = 1.0f - fz;
        const int lx0 = (int)x0f - XS;   // in [0,32]; +1 <= 33
        const int ly0 = (int)y0f - YS;   // in [0,8];  +1 <= 9
        const int lz0 = (int)z0f - ZS;   // in [0,4];  +1 <= 5

        const int rY0 = ly0 * LS_X, rY1 = rY0 + LS_X;
        const int rZ0 = lz0 * (LS_Y * LS_X), rZ1 = rZ0 + LS_Y * LS_X;
        const int rb4[4] = { rZ0 + rY0 + lx0, rZ0 + rY1 + lx0,
                             rZ1 + rY0 + lx0, rZ1 + rY1 + lx0 };

        float r0, r1, r2;
        float* rr[3] = { &r0, &r1, &r2 };
        #pragma unroll
        for (int c = 0; c < 3; ++c) {
            const int co = c * LREG;
            float g[4];
            #pragma unroll
            for (int qq = 0; qq < 4; ++qq) {
                float A = sm[co + rb4[qq]];
                float B = sm[co + rb4[qq] + 1];
                g[qq] = A * ofx + B * fx;
            }
            *rr[c] = (g[0] * ofy + g[1] * fy) * ofz + (g[2] * ofy + g[3] * fy) * fz;
        }

        const int pidx = (z * S + y) * S + x;
        dst[pidx]           = w0 + r0;
        dst[pidx + VOX]     = w1 + r1;
        dst[pidx + 2 * VOX] = w2 + r2;
    }
}

// ---------- layout copy: planar -> brick (scaled) ----------
__global__ __launch_bounds__(THREADS) void svf_copy(const float* __restrict__ src,
                                                    float* __restrict__ dst,
                                                    float scale) {
    const int b   = blockIdx.x;
    const int blk = (b & (NXCD - 1)) * BCHUNK + (b >> 3);
    const int bx = blk % 5;
    const int by = (blk / 5) % 40;
    const int bz = blk / 200;

    const int tid = threadIdx.x;
    const int x = bx * 32 + (tid & 31);
    const int y = by * 4 + ((tid >> 5) & 3);
    const int z = bz * 2 + (tid >> 7);

    const int idx = (z * S + y) * S + x;
    const float w0 = src[idx] * scale;
    const float w1 = src[idx + VOX] * scale;
    const float w2 = src[idx + 2 * VOX] * scale;

    const int f = brickf(x, y, z);
    float2 st = make_float2(w0, w1);
    __builtin_memcpy(dst + f, &st, 8);
    dst[f + 2] = w2;
}

// ---------- Phase B: brick global-gather step (round-7 proven) ----------
// MODE 1: brick -> brick.  MODE 2: brick -> planar + identity.
template <int MODE>
__global__ __launch_bounds__(THREADS) void svf_step(const float* __restrict__ src,
                                                    float* __restrict__ dst) {
    const int b   = blockIdx.x;
    const int blk = (b & (NXCD - 1)) * BCHUNK + (b >> 3);
    const int m   = blk * THREADS + threadIdx.x;   // brick-linear voxel id

    const int lr = m & 3;
    const int t  = m >> 2;
    const int x  = t % S;
    const int u  = t / S;
    const int y  = (u % 80) * 2 + (lr & 1);
    const int z  = (u / 80) * 2 + (lr >> 1);

    const int f = m * 3;

    float4 own = ld4u(src + f);
    const float w0 = own.x, w1 = own.y, w2 = own.z;

    float gx = fminf(fmaxf(fmaf(80.0f, w0, (float)x), 0.0f), 159.0f);
    float gy = fminf(fmaxf(fmaf(80.0f, w1, (float)y), 0.0f), 159.0f);
    float gz = fminf(fmaxf(fmaf(80.0f, w2, (float)z), 0.0f), 159.0f);

    const float x0f = floorf(gx), y0f = floorf(gy), z0f = floorf(gz);
    const float fx = gx - x0f, fy = gy - y0f, fz = gz - z0f;
    const int x0 = (int)x0f, y0 = (int)y0f, z0 = (int)z0f;
    const int x1 = min(x0 + 1, S - 1);
    const int y1 = min(y0 + 1, S - 1);
    const int z1 = min(z0 + 1, S - 1);
    const float ofx = 1.0f - fx, ofy = 1.0f - fy, ofz = 1.0f - fz;

    const int Y0 = (y0 >> 1) * 1920 + (y0 & 1) * 3;   // 1920 = 160*4*3
    const int Y1 = (y1 >> 1) * 1920 + (y1 & 1) * 3;
    const int Z0 = (z0 >> 1) * 153600 + (z0 & 1) * 6; // 153600 = 80*160*4*3
    const int Z1 = (z1 >> 1) * 153600 + (z1 & 1) * 6;
    const int rb4[4] = { Z0 + Y0, Z0 + Y1, Z1 + Y0, Z1 + Y1 };

    const int xo0 = x0 * 12, xo1 = x1 * 12;
    float g0[4], g1[4], g2[4];
    #pragma unroll
    for (int q = 0; q < 4; ++q) {
        float4 A = ld4u(src + rb4[q] + xo0);
        float4 B = ld4u(src + rb4[q] + xo1);
        g0[q] = A.x * ofx + B.x * fx;
        g1[q] = A.y * ofx + B.y * fx;
        g2[q] = A.z * ofx + B.z * fx;
    }
    float r0 = (g0[0] * ofy + g0[1] * fy) * ofz + (g0[2] * ofy + g0[3] * fy) * fz;
    float r1 = (g1[0] * ofy + g1[1] * fy) * ofz + (g1[2] * ofy + g1[3] * fy) * fz;
    float r2 = (g2[0] * ofy + g2[1] * fy) * ofz + (g2[2] * ofy + g2[3] * fy) * fz;

    const float n0 = w0 + r0;
    const float n1 = w1 + r1;
    const float n2 = w2 + r2;

    if (MODE == 2) {
        const int pidx = (z * S + y) * S + x;
        dst[pidx]           = idcoord(x) + n0;
        dst[pidx + VOX]     = idcoord(y) + n1;
        dst[pidx + 2 * VOX] = idcoord(z) + n2;
    } else {
        float2 st = make_float2(n0, n1);
        __builtin_memcpy(dst + f, &st, 8);
        dst[f + 2] = n2;
    }
}

extern "C" void kernel_launch(void* const* d_in, const int* in_sizes, int n_in,
                              void* d_out, int out_size, void* d_ws, size_t ws_size,
                              hipStream_t stream) {
    // in[0] = identity_grid (recomputed analytically), in[1] = v
    const float* v = (const float*)d_in[1];
    float* out = (float*)d_out;
    float* ws  = (float*)d_ws;   // 3*160^3*4 = 49.15 MB used

    const float s = 1.0f / 65536.0f;  // 2^-16, exact

    // Phase A: steps 1..8, planar LDS-gather. Parity: odd steps -> out, even -> ws.
    svf_lds<<<LBLOCKS, THREADS, 0, stream>>>(v,   out, s);     // w1
    svf_lds<<<LBLOCKS, THREADS, 0, stream>>>(out, ws,  1.0f);  // w2
    svf_lds<<<LBLOCKS, THREADS, 0, stream>>>(ws,  out, 1.0f);  // w3
    svf_lds<<<LBLOCKS, THREADS, 0, stream>>>(out, ws,  1.0f);  // w4
    svf_lds<<<LBLOCKS, THREADS, 0, stream>>>(ws,  out, 1.0f);  // w5
    svf_lds<<<LBLOCKS, THREADS, 0, stream>>>(out, ws,  1.0f);  // w6
    svf_lds<<<LBLOCKS, THREADS, 0, stream>>>(ws,  out, 1.0f);  // w7
    svf_lds<<<LBLOCKS, THREADS, 0, stream>>>(out, ws,  1.0f);  // w8 (planar, in ws)

    // layout transition: w8 planar -> brick
    svf_copy<<<BBLOCKS, THREADS, 0, stream>>>(ws, out, 1.0f);  // w8 brick in out

    // Phase B: steps 9..15 brick, then final
    svf_step<1><<<BBLOCKS, THREADS, 0, stream>>>(out, ws);   // w9
    svf_step<1><<<BBLOCKS, THREADS, 0, stream>>>(ws, out);   // w10
    svf_step<1><<<BBLOCKS, THREADS, 0, stream>>>(out, ws);   // w11
    svf_step<1><<<BBLOCKS, THREADS, 0, stream>>>(ws, out);   // w12
    svf_step<1><<<BBLOCKS, THREADS, 0, stream>>>(out, ws);   // w13
    svf_step<1><<<BBLOCKS, THREADS, 0, stream>>>(ws, out);   // w14
    svf_step<1><<<BBLOCKS, THREADS, 0, stream>>>(out, ws);   // w15 (brick, in ws)
    svf_step<2><<<BBLOCKS, THREADS, 0, stream>>>(ws, out);   // out = id + w16, planar
}

// Round 10
// 574.044 us; speedup vs baseline: 1.5163x; 1.0513x over previous
//
#include <hip/hip_runtime.h>

// SVF scaling-and-squaring: 16 steps of warp <- warp + sample(warp, id + warp)
// Brick layout: float index of voxel (x,y,z) =
//   ((((z>>1)*80 + (y>>1))*160 + x)*4 + ((z&1)*2 + (y&1))) * 3
// Round-7 structure (copy + 15 brick steps + final); this round forces all
// 8 gather dwordx4s into flight (named regs, loads clustered before use)
// under __launch_bounds__(256,8) (<=64 VGPR keeps 32 waves/CU). Round-7's
// 24-VGPR compile serialized the gather into ~3 latency phases; round-8's
// 2-voxel variant overflowed to 44 VGPR and halved waves. One voxel/thread
// + full MLP is the middle path.
// LDS gather (round 9) regressed: 27 scalar ds_reads/voxel is slower than
// vectorized L1/L2 gather. Reverted.

constexpr int S   = 160;
constexpr int VOX = S * S * S;        // 4,096,000
constexpr int THREADS = 256;
constexpr int BLOCKS  = VOX / THREADS;   // 16000
constexpr int NXCD  = 8;
constexpr int CHUNK = BLOCKS / NXCD;     // 2000

__device__ __forceinline__ float idcoord(int u) {
    // matches jnp: (2.0*arange + 1.0)/160.0 - 1.0 in fp32
    return (2.0f * (float)u + 1.0f) / 160.0f - 1.0f;
}

__device__ __forceinline__ float4 ld4u(const float* p) { float4 r; __builtin_memcpy(&r, p, 16); return r; }

// brick float-index of voxel (x,y,z)
__device__ __forceinline__ int brickf(int x, int y, int z) {
    return ((((z >> 1) * 80 + (y >> 1)) * S + x) * 4 + ((z & 1) * 2 + (y & 1))) * 3;
}

// Copy: v planar -> brick, scaled by 2^-16 (exact). 32x4x2 tile per block.
__global__ __launch_bounds__(THREADS) void svf_copy(const float* __restrict__ src,
                                                    float* __restrict__ dst,
                                                    float scale) {
    const int b   = blockIdx.x;
    const int blk = (b & (NXCD - 1)) * CHUNK + (b >> 3);
    const int bx = blk % 5;
    const int by = (blk / 5) % 40;
    const int bz = blk / 200;

    const int tid = threadIdx.x;
    const int x = bx * 32 + (tid & 31);
    const int y = by * 4 + ((tid >> 5) & 3);
    const int z = bz * 2 + (tid >> 7);

    const int idx = (z * S + y) * S + x;
    const float w0 = src[idx] * scale;
    const float w1 = src[idx + VOX] * scale;
    const float w2 = src[idx + 2 * VOX] * scale;

    const int f = brickf(x, y, z);
    float2 st = make_float2(w0, w1);
    __builtin_memcpy(dst + f, &st, 8);
    dst[f + 2] = w2;
}

// MODE 1: brick -> brick.  MODE 2: brick -> planar + identity.
template <int MODE>
__global__ __launch_bounds__(THREADS, 8) void svf_step(const float* __restrict__ src,
                                                       float* __restrict__ dst) {
    const int b   = blockIdx.x;
    const int blk = (b & (NXCD - 1)) * CHUNK + (b >> 3);
    const int m   = blk * THREADS + threadIdx.x;   // brick-linear voxel id

    const int lr = m & 3;
    const int t  = m >> 2;
    const int x  = t % S;
    const int u  = t / S;
    const int y  = (u % 80) * 2 + (lr & 1);
    const int z  = (u / 80) * 2 + (lr >> 1);

    const int f = m * 3;

    float4 own = ld4u(src + f);
    const float w0 = own.x, w1 = own.y, w2 = own.z;

    float gx = fminf(fmaxf(fmaf(80.0f, w0, (float)x), 0.0f), 159.0f);
    float gy = fminf(fmaxf(fmaf(80.0f, w1, (float)y), 0.0f), 159.0f);
    float gz = fminf(fmaxf(fmaf(80.0f, w2, (float)z), 0.0f), 159.0f);

    const float x0f = floorf(gx), y0f = floorf(gy), z0f = floorf(gz);
    const float fx = gx - x0f, fy = gy - y0f, fz = gz - z0f;
    const int x0 = (int)x0f, y0 = (int)y0f, z0 = (int)z0f;
    const int x1 = min(x0 + 1, S - 1);
    const int y1 = min(y0 + 1, S - 1);
    const int z1 = min(z0 + 1, S - 1);
    const float ofx = 1.0f - fx, ofy = 1.0f - fy, ofz = 1.0f - fz;

    const int Y0 = (y0 >> 1) * 1920 + (y0 & 1) * 3;   // 1920 = 160*4*3
    const int Y1 = (y1 >> 1) * 1920 + (y1 & 1) * 3;
    const int Z0 = (z0 >> 1) * 153600 + (z0 & 1) * 6; // 153600 = 80*160*4*3
    const int Z1 = (z1 >> 1) * 153600 + (z1 & 1) * 6;

    const int xo0 = x0 * 12, xo1 = x1 * 12;
    const int r0a = Z0 + Y0, r1a = Z0 + Y1, r2a = Z1 + Y0, r3a = Z1 + Y1;

    // all 8 row-loads issued back-to-back: full memory-level parallelism
    const float4 A0 = ld4u(src + r0a + xo0);
    const float4 B0 = ld4u(src + r0a + xo1);
    const float4 A1 = ld4u(src + r1a + xo0);
    const float4 B1 = ld4u(src + r1a + xo1);
    const float4 A2 = ld4u(src + r2a + xo0);
    const float4 B2 = ld4u(src + r2a + xo1);
    const float4 A3 = ld4u(src + r3a + xo0);
    const float4 B3 = ld4u(src + r3a + xo1);

    const float g00 = A0.x * ofx + B0.x * fx;
    const float g10 = A0.y * ofx + B0.y * fx;
    const float g20 = A0.z * ofx + B0.z * fx;
    const float g01 = A1.x * ofx + B1.x * fx;
    const float g11 = A1.y * ofx + B1.y * fx;
    const float g21 = A1.z * ofx + B1.z * fx;
    const float g02 = A2.x * ofx + B2.x * fx;
    const float g12 = A2.y * ofx + B2.y * fx;
    const float g22 = A2.z * ofx + B2.z * fx;
    const float g03 = A3.x * ofx + B3.x * fx;
    const float g13 = A3.y * ofx + B3.y * fx;
    const float g23 = A3.z * ofx + B3.z * fx;

    const float r0 = (g00 * ofy + g01 * fy) * ofz + (g02 * ofy + g03 * fy) * fz;
    const float r1 = (g10 * ofy + g11 * fy) * ofz + (g12 * ofy + g13 * fy) * fz;
    const float r2 = (g20 * ofy + g21 * fy) * ofz + (g22 * ofy + g23 * fy) * fz;

    const float n0 = w0 + r0;
    const float n1 = w1 + r1;
    const float n2 = w2 + r2;

    if (MODE == 2) {
        const int pidx = (z * S + y) * S + x;
        dst[pidx]           = idcoord(x) + n0;
        dst[pidx + VOX]     = idcoord(y) + n1;
        dst[pidx + 2 * VOX] = idcoord(z) + n2;
    } else {
        float2 st = make_float2(n0, n1);
        __builtin_memcpy(dst + f, &st, 8);
        dst[f + 2] = n2;
    }
}

extern "C" void kernel_launch(void* const* d_in, const int* in_sizes, int n_in,
                              void* d_out, int out_size, void* d_ws, size_t ws_size,
                              hipStream_t stream) {
    // in[0] = identity_grid (recomputed analytically), in[1] = v
    const float* v = (const float*)d_in[1];
    float* out = (float*)d_out;
    float* ws  = (float*)d_ws;   // 3*160^3*4 = 49.15 MB used

    const float s = 1.0f / 65536.0f;  // 2^-16, exact

    // init: v (planar, scaled) -> out used as brick scratch
    svf_copy<<<BLOCKS, THREADS, 0, stream>>>(v, out, s);
    // steps 1..15: ping-pong; odd step -> ws, even step -> out.
    // step 15 lands in ws, so the final pass reads ws and writes out (planar).
    for (int k = 1; k <= 15; ++k) {
        if (k & 1)
            svf_step<1><<<BLOCKS, THREADS, 0, stream>>>(out, ws);
        else
            svf_step<1><<<BLOCKS, THREADS, 0, stream>>>(ws, out);
    }
    // step 16: ws (brick) -> d_out planar + identity
    svf_step<2><<<BLOCKS, THREADS, 0, stream>>>(ws, out);
}

// Round 11
// 571.091 us; speedup vs baseline: 1.5241x; 1.0052x over previous
//
#include <hip/hip_runtime.h>

// SVF scaling-and-squaring: 16 steps of warp <- warp + sample(warp, id + warp)
// Brick layout: float index of voxel (x,y,z) =
//   ((((z>>1)*80 + (y>>1))*160 + x)*4 + ((z&1)*2 + (y&1))) * 3
// Gather MLP is forced with ONE inline-asm block issuing all 8
// global_load_dwordx4 back-to-back (+ s_waitcnt vmcnt(0)) with early-clobber
// outputs: the HIP compiler otherwise re-serializes to ~2-3 loads in flight
// (observed VGPR=24 across rounds 7/10 despite source-level clustering).
// History: LDS gather (r9) and 2-voxel/thread (r8) both regressed; NT stores
// regressed (r5); fast position math gx = x + 80*w replaces the reference
// divide chain (absmax 0.0156->0.0234, within tolerance).

constexpr int S   = 160;
constexpr int VOX = S * S * S;        // 4,096,000
constexpr int THREADS = 256;
constexpr int BLOCKS  = VOX / THREADS;   // 16000
constexpr int NXCD  = 8;
constexpr int CHUNK = BLOCKS / NXCD;     // 2000

typedef float f32x4 __attribute__((ext_vector_type(4)));

__device__ __forceinline__ float idcoord(int u) {
    // matches jnp: (2.0*arange + 1.0)/160.0 - 1.0 in fp32
    return (2.0f * (float)u + 1.0f) / 160.0f - 1.0f;
}

__device__ __forceinline__ float4 ld4u(const float* p) { float4 r; __builtin_memcpy(&r, p, 16); return r; }

// brick float-index of voxel (x,y,z)
__device__ __forceinline__ int brickf(int x, int y, int z) {
    return ((((z >> 1) * 80 + (y >> 1)) * S + x) * 4 + ((z & 1) * 2 + (y & 1))) * 3;
}

// Copy: v planar -> brick, scaled by 2^-16 (exact). 32x4x2 tile per block.
__global__ __launch_bounds__(THREADS) void svf_copy(const float* __restrict__ src,
                                                    float* __restrict__ dst,
                                                    float scale) {
    const int b   = blockIdx.x;
    const int blk = (b & (NXCD - 1)) * CHUNK + (b >> 3);
    const int bx = blk % 5;
    const int by = (blk / 5) % 40;
    const int bz = blk / 200;

    const int tid = threadIdx.x;
    const int x = bx * 32 + (tid & 31);
    const int y = by * 4 + ((tid >> 5) & 3);
    const int z = bz * 2 + (tid >> 7);

    const int idx = (z * S + y) * S + x;
    const float w0 = src[idx] * scale;
    const float w1 = src[idx + VOX] * scale;
    const float w2 = src[idx + 2 * VOX] * scale;

    const int f = brickf(x, y, z);
    float2 st = make_float2(w0, w1);
    __builtin_memcpy(dst + f, &st, 8);
    dst[f + 2] = w2;
}

// MODE 1: brick -> brick.  MODE 2: brick -> planar + identity.
template <int MODE>
__global__ __launch_bounds__(THREADS, 8) void svf_step(const float* __restrict__ src,
                                                       float* __restrict__ dst) {
    const int b   = blockIdx.x;
    const int blk = (b & (NXCD - 1)) * CHUNK + (b >> 3);
    const int m   = blk * THREADS + threadIdx.x;   // brick-linear voxel id

    const int lr = m & 3;
    const int t  = m >> 2;
    const int x  = t % S;
    const int u  = t / S;
    const int y  = (u % 80) * 2 + (lr & 1);
    const int z  = (u / 80) * 2 + (lr >> 1);

    const int f = m * 3;

    float4 own = ld4u(src + f);
    const float w0 = own.x, w1 = own.y, w2 = own.z;

    float gx = fminf(fmaxf(fmaf(80.0f, w0, (float)x), 0.0f), 159.0f);
    float gy = fminf(fmaxf(fmaf(80.0f, w1, (float)y), 0.0f), 159.0f);
    float gz = fminf(fmaxf(fmaf(80.0f, w2, (float)z), 0.0f), 159.0f);

    const float x0f = floorf(gx), y0f = floorf(gy), z0f = floorf(gz);
    const float fx = gx - x0f, fy = gy - y0f, fz = gz - z0f;
    const int x0 = (int)x0f, y0 = (int)y0f, z0 = (int)z0f;
    const float ofx = 1.0f - fx, ofy = 1.0f - fy, ofz = 1.0f - fz;

    const int Y0 = (y0 >> 1) * 1920 + (y0 & 1) * 3;   // 1920 = 160*4*3
    const int Y1 = (min(y0 + 1, S - 1) >> 1) * 1920 + (min(y0 + 1, S - 1) & 1) * 3;
    const int Z0 = (z0 >> 1) * 153600 + (z0 & 1) * 6; // 153600 = 80*160*4*3
    const int Z1 = (min(z0 + 1, S - 1) >> 1) * 153600 + (min(z0 + 1, S - 1) & 1) * 6;

    const int xo0 = x0 * 12, xo1 = min(x0 + 1, S - 1) * 12;

    const float* p0 = src + (Z0 + Y0) + xo0;
    const float* q0 = src + (Z0 + Y0) + xo1;
    const float* p1 = src + (Z0 + Y1) + xo0;
    const float* q1 = src + (Z0 + Y1) + xo1;
    const float* p2 = src + (Z1 + Y0) + xo0;
    const float* q2 = src + (Z1 + Y0) + xo1;
    const float* p3 = src + (Z1 + Y1) + xo0;
    const float* q3 = src + (Z1 + Y1) + xo1;

    f32x4 A0, B0, A1, B1, A2, B2, A3, B3;
    // all 8 row-loads in ONE asm block: forced 8-deep MLP, single wait
    asm volatile(
        "global_load_dwordx4 %0, %8, off\n\t"
        "global_load_dwordx4 %1, %9, off\n\t"
        "global_load_dwordx4 %2, %10, off\n\t"
        "global_load_dwordx4 %3, %11, off\n\t"
        "global_load_dwordx4 %4, %12, off\n\t"
        "global_load_dwordx4 %5, %13, off\n\t"
        "global_load_dwordx4 %6, %14, off\n\t"
        "global_load_dwordx4 %7, %15, off\n\t"
        "s_waitcnt vmcnt(0)"
        : "=&v"(A0), "=&v"(B0), "=&v"(A1), "=&v"(B1),
          "=&v"(A2), "=&v"(B2), "=&v"(A3), "=&v"(B3)
        : "v"(p0), "v"(q0), "v"(p1), "v"(q1),
          "v"(p2), "v"(q2), "v"(p3), "v"(q3));

    const float g00 = A0.x * ofx + B0.x * fx;
    const float g10 = A0.y * ofx + B0.y * fx;
    const float g20 = A0.z * ofx + B0.z * fx;
    const float g01 = A1.x * ofx + B1.x * fx;
    const float g11 = A1.y * ofx + B1.y * fx;
    const float g21 = A1.z * ofx + B1.z * fx;
    const float g02 = A2.x * ofx + B2.x * fx;
    const float g12 = A2.y * ofx + B2.y * fx;
    const float g22 = A2.z * ofx + B2.z * fx;
    const float g03 = A3.x * ofx + B3.x * fx;
    const float g13 = A3.y * ofx + B3.y * fx;
    const float g23 = A3.z * ofx + B3.z * fx;

    const float r0 = (g00 * ofy + g01 * fy) * ofz + (g02 * ofy + g03 * fy) * fz;
    const float r1 = (g10 * ofy + g11 * fy) * ofz + (g12 * ofy + g13 * fy) * fz;
    const float r2 = (g20 * ofy + g21 * fy) * ofz + (g22 * ofy + g23 * fy) * fz;

    const float n0 = w0 + r0;
    const float n1 = w1 + r1;
    const float n2 = w2 + r2;

    if (MODE == 2) {
        const int pidx = (z * S + y) * S + x;
        dst[pidx]           = idcoord(x) + n0;
        dst[pidx + VOX]     = idcoord(y) + n1;
        dst[pidx + 2 * VOX] = idcoord(z) + n2;
    } else {
        float2 st = make_float2(n0, n1);
        __builtin_memcpy(dst + f, &st, 8);
        dst[f + 2] = n2;
    }
}

extern "C" void kernel_launch(void* const* d_in, const int* in_sizes, int n_in,
                              void* d_out, int out_size, void* d_ws, size_t ws_size,
                              hipStream_t stream) {
    // in[0] = identity_grid (recomputed analytically), in[1] = v
    const float* v = (const float*)d_in[1];
    float* out = (float*)d_out;
    float* ws  = (float*)d_ws;   // 3*160^3*4 = 49.15 MB used

    const float s = 1.0f / 65536.0f;  // 2^-16, exact

    // init: v (planar, scaled) -> out used as brick scratch
    svf_copy<<<BLOCKS, THREADS, 0, stream>>>(v, out, s);
    // steps 1..15: ping-pong; odd step -> ws, even step -> out.
    // step 15 lands in ws, so the final pass reads ws and writes out (planar).
    for (int k = 1; k <= 15; ++k) {
        if (k & 1)
            svf_step<1><<<BLOCKS, THREADS, 0, stream>>>(out, ws);
        else
            svf_step<1><<<BLOCKS, THREADS, 0, stream>>>(ws, out);
    }
    // step 16: ws (brick) -> d_out planar + identity
    svf_step<2><<<BLOCKS, THREADS, 0, stream>>>(ws, out);
}

// Round 12
// 567.189 us; speedup vs baseline: 1.5346x; 1.0069x over previous
//
#include <hip/hip_runtime.h>

// SVF scaling-and-squaring: 16 steps of warp <- warp + sample(warp, id + warp)
// Brick layout: float index of voxel (x,y,z) =
//   ((((z>>1)*80 + (y>>1))*160 + x)*4 + ((z&1)*2 + (y&1))) * 3
// Step kernels: 640-thread blocks (one x-row of units = 160 units x 4 lr),
// grid (8,80,10): blockIdx.x = XCD chunk (linear-id mod 8 round-robin),
// zb = bx*10 + bz -> each XCD owns 20 contiguous z-slices (same slabs as
// the copy kernel). Thread decode is pure shifts; row terms are SALU.
// History: NT stores regressed (r5); LDS gather regressed (r9); 2-voxel/
// thread regressed at 44 VGPR (r8); asm-forced 8-load MLP neutral (r10/11);
// fast position math gx = x + 80*w (absmax 0.0156->0.0234, passes).

constexpr int S   = 160;
constexpr int VOX = S * S * S;        // 4,096,000
constexpr int CTHREADS = 256;
constexpr int CBLOCKS  = VOX / CTHREADS;   // 16000 (copy kernel)
constexpr int NXCD  = 8;
constexpr int CCHUNK = CBLOCKS / NXCD;     // 2000
constexpr int STHREADS = 640;              // 160 units x 4 lr

__device__ __forceinline__ float idcoord(int u) {
    // matches jnp: (2.0*arange + 1.0)/160.0 - 1.0 in fp32
    return (2.0f * (float)u + 1.0f) / 160.0f - 1.0f;
}

__device__ __forceinline__ float4 ld4u(const float* p) { float4 r; __builtin_memcpy(&r, p, 16); return r; }

// brick float-index of voxel (x,y,z)
__device__ __forceinline__ int brickf(int x, int y, int z) {
    return ((((z >> 1) * 80 + (y >> 1)) * S + x) * 4 + ((z & 1) * 2 + (y & 1))) * 3;
}

// Copy: v planar -> brick, scaled by 2^-16 (exact). 32x4x2 tile per block.
__global__ __launch_bounds__(CTHREADS) void svf_copy(const float* __restrict__ src,
                                                     float* __restrict__ dst,
                                                     float scale) {
    const int b   = blockIdx.x;
    const int blk = (b & (NXCD - 1)) * CCHUNK + (b >> 3);
    const int bx = blk % 5;
    const int by = (blk / 5) % 40;
    const int bz = blk / 200;

    const int tid = threadIdx.x;
    const int x = bx * 32 + (tid & 31);
    const int y = by * 4 + ((tid >> 5) & 3);
    const int z = bz * 2 + (tid >> 7);

    const int idx = (z * S + y) * S + x;
    const float w0 = src[idx] * scale;
    const float w1 = src[idx + VOX] * scale;
    const float w2 = src[idx + 2 * VOX] * scale;

    const int f = brickf(x, y, z);
    float2 st = make_float2(w0, w1);
    __builtin_memcpy(dst + f, &st, 8);
    dst[f + 2] = w2;
}

// MODE 1: brick -> brick.  MODE 2: brick -> planar + identity.
// Grid (8, 80, 10), block 640. zb = bx*10 + bz, yb = by.
template <int MODE>
__global__ __launch_bounds__(STHREADS) void svf_step(const float* __restrict__ src,
                                                     float* __restrict__ dst) {
    const int lr = threadIdx.x & 3;
    const int x  = threadIdx.x >> 2;          // [0,160)
    const int zb = blockIdx.x * 10 + blockIdx.z;
    const int yb = blockIdx.y;
    const int row = zb * 80 + yb;             // block-uniform (SALU)
    const int y = yb * 2 + (lr & 1);
    const int z = zb * 2 + (lr >> 1);

    const int f = row * 1920 + x * 12 + lr * 3;   // own float index

    float4 own = ld4u(src + f);
    const float w0 = own.x, w1 = own.y, w2 = own.z;

    float gx = fminf(fmaxf(fmaf(80.0f, w0, (float)x), 0.0f), 159.0f);
    float gy = fminf(fmaxf(fmaf(80.0f, w1, (float)y), 0.0f), 159.0f);
    float gz = fminf(fmaxf(fmaf(80.0f, w2, (float)z), 0.0f), 159.0f);

    const float x0f = floorf(gx), y0f = floorf(gy), z0f = floorf(gz);
    const float fx = gx - x0f, fy = gy - y0f, fz = gz - z0f;
    const int x0 = (int)x0f, y0 = (int)y0f, z0 = (int)z0f;
    const int x1 = min(x0 + 1, S - 1);
    const int y1 = min(y0 + 1, S - 1);
    const int z1 = min(z0 + 1, S - 1);
    const float ofx = 1.0f - fx, ofy = 1.0f - fy, ofz = 1.0f - fz;

    const int Y0 = (y0 >> 1) * 1920 + (y0 & 1) * 3;   // 1920 = 160*4*3
    const int Y1 = (y1 >> 1) * 1920 + (y1 & 1) * 3;
    const int Z0 = (z0 >> 1) * 153600 + (z0 & 1) * 6; // 153600 = 80*160*4*3
    const int Z1 = (z1 >> 1) * 153600 + (z1 & 1) * 6;
    const int rb4[4] = { Z0 + Y0, Z0 + Y1, Z1 + Y0, Z1 + Y1 };

    const int xo0 = x0 * 12, xo1 = x1 * 12;
    float g0[4], g1[4], g2[4];
    #pragma unroll
    for (int q = 0; q < 4; ++q) {
        float4 A = ld4u(src + rb4[q] + xo0);
        float4 B = ld4u(src + rb4[q] + xo1);
        g0[q] = A.x * ofx + B.x * fx;
        g1[q] = A.y * ofx + B.y * fx;
        g2[q] = A.z * ofx + B.z * fx;
    }
    float r0 = (g0[0] * ofy + g0[1] * fy) * ofz + (g0[2] * ofy + g0[3] * fy) * fz;
    float r1 = (g1[0] * ofy + g1[1] * fy) * ofz + (g1[2] * ofy + g1[3] * fy) * fz;
    float r2 = (g2[0] * ofy + g2[1] * fy) * ofz + (g2[2] * ofy + g2[3] * fy) * fz;

    const float n0 = w0 + r0;
    const float n1 = w1 + r1;
    const float n2 = w2 + r2;

    if (MODE == 2) {
        const int pidx = (z * S + y) * S + x;
        dst[pidx]           = idcoord(x) + n0;
        dst[pidx + VOX]     = idcoord(y) + n1;
        dst[pidx + 2 * VOX] = idcoord(z) + n2;
    } else {
        float2 st = make_float2(n0, n1);
        __builtin_memcpy(dst + f, &st, 8);
        dst[f + 2] = n2;
    }
}

extern "C" void kernel_launch(void* const* d_in, const int* in_sizes, int n_in,
                              void* d_out, int out_size, void* d_ws, size_t ws_size,
                              hipStream_t stream) {
    // in[0] = identity_grid (recomputed analytically), in[1] = v
    const float* v = (const float*)d_in[1];
    float* out = (float*)d_out;
    float* ws  = (float*)d_ws;   // 3*160^3*4 = 49.15 MB used

    const float s = 1.0f / 65536.0f;  // 2^-16, exact

    dim3 sgrid(NXCD, 80, 10);   // linear id mod 8 = blockIdx.x = XCD chunk

    // init: v (planar, scaled) -> out used as brick scratch
    svf_copy<<<CBLOCKS, CTHREADS, 0, stream>>>(v, out, s);
    // steps 1..15: ping-pong; odd step -> ws, even step -> out.
    // step 15 lands in ws, so the final pass reads ws and writes out (planar).
    for (int k = 1; k <= 15; ++k) {
        if (k & 1)
            svf_step<1><<<sgrid, STHREADS, 0, stream>>>(out, ws);
        else
            svf_step<1><<<sgrid, STHREADS, 0, stream>>>(ws, out);
    }
    // step 16: ws (brick) -> d_out planar + identity
    svf_step<2><<<sgrid, STHREADS, 0, stream>>>(ws, out);
}

// Round 13
// 558.926 us; speedup vs baseline: 1.5573x; 1.0148x over previous
//
#include <hip/hip_runtime.h>

// SVF scaling-and-squaring: 16 steps of warp <- warp + sample(warp, id + warp)
// Brick layout: float index of voxel (x,y,z) =
//   ((((z>>1)*80 + (y>>1))*160 + x)*4 + ((z&1)*2 + (y&1))) * 3
// r7-proven structure: copy + 15 brick steps (256-thread, XCD-chunked) +
// final. This round: final step uses the copy-kernel's planar 32x4x2 tile
// mapping so its planar stores are coalesced (was: 64-lane stride-640B).
// Ruled out by measurement: NT stores (r5), LDS gather (r9), 2 voxels/thread
// (r8), asm-forced 8-load MLP (r10/11), 640-thread SALU decode (r12).
// Late steps are L1-transaction-bound on random gathers (~43 us floor).

constexpr int S   = 160;
constexpr int VOX = S * S * S;        // 4,096,000
constexpr int THREADS = 256;
constexpr int BLOCKS  = VOX / THREADS;   // 16000
constexpr int NXCD  = 8;
constexpr int CHUNK = BLOCKS / NXCD;     // 2000

__device__ __forceinline__ float idcoord(int u) {
    // matches jnp: (2.0*arange + 1.0)/160.0 - 1.0 in fp32
    return (2.0f * (float)u + 1.0f) / 160.0f - 1.0f;
}

__device__ __forceinline__ float4 ld4u(const float* p) { float4 r; __builtin_memcpy(&r, p, 16); return r; }

// brick float-index of voxel (x,y,z)
__device__ __forceinline__ int brickf(int x, int y, int z) {
    return ((((z >> 1) * 80 + (y >> 1)) * S + x) * 4 + ((z & 1) * 2 + (y & 1))) * 3;
}

// shared gather: 8 corner rows from brick layout + trilinear combine
__device__ __forceinline__ void brick_gather(const float* __restrict__ src,
                                             int x, int y, int z,
                                             float w0, float w1, float w2,
                                             float& n0, float& n1, float& n2) {
    float gx = fminf(fmaxf(fmaf(80.0f, w0, (float)x), 0.0f), 159.0f);
    float gy = fminf(fmaxf(fmaf(80.0f, w1, (float)y), 0.0f), 159.0f);
    float gz = fminf(fmaxf(fmaf(80.0f, w2, (float)z), 0.0f), 159.0f);

    const float x0f = floorf(gx), y0f = floorf(gy), z0f = floorf(gz);
    const float fx = gx - x0f, fy = gy - y0f, fz = gz - z0f;
    const int x0 = (int)x0f, y0 = (int)y0f, z0 = (int)z0f;
    const int x1 = min(x0 + 1, S - 1);
    const int y1 = min(y0 + 1, S - 1);
    const int z1 = min(z0 + 1, S - 1);
    const float ofx = 1.0f - fx, ofy = 1.0f - fy, ofz = 1.0f - fz;

    const int Y0 = (y0 >> 1) * 1920 + (y0 & 1) * 3;   // 1920 = 160*4*3
    const int Y1 = (y1 >> 1) * 1920 + (y1 & 1) * 3;
    const int Z0 = (z0 >> 1) * 153600 + (z0 & 1) * 6; // 153600 = 80*160*4*3
    const int Z1 = (z1 >> 1) * 153600 + (z1 & 1) * 6;
    const int rb4[4] = { Z0 + Y0, Z0 + Y1, Z1 + Y0, Z1 + Y1 };

    const int xo0 = x0 * 12, xo1 = x1 * 12;
    float g0[4], g1[4], g2[4];
    #pragma unroll
    for (int q = 0; q < 4; ++q) {
        float4 A = ld4u(src + rb4[q] + xo0);
        float4 B = ld4u(src + rb4[q] + xo1);
        g0[q] = A.x * ofx + B.x * fx;
        g1[q] = A.y * ofx + B.y * fx;
        g2[q] = A.z * ofx + B.z * fx;
    }
    float r0 = (g0[0] * ofy + g0[1] * fy) * ofz + (g0[2] * ofy + g0[3] * fy) * fz;
    float r1 = (g1[0] * ofy + g1[1] * fy) * ofz + (g1[2] * ofy + g1[3] * fy) * fz;
    float r2 = (g2[0] * ofy + g2[1] * fy) * ofz + (g2[2] * ofy + g2[3] * fy) * fz;

    n0 = w0 + r0;
    n1 = w1 + r1;
    n2 = w2 + r2;
}

// Copy: v planar -> brick, scaled by 2^-16 (exact). 32x4x2 tile per block.
__global__ __launch_bounds__(THREADS) void svf_copy(const float* __restrict__ src,
                                                    float* __restrict__ dst,
                                                    float scale) {
    const int b   = blockIdx.x;
    const int blk = (b & (NXCD - 1)) * CHUNK + (b >> 3);
    const int bx = blk % 5;
    const int by = (blk / 5) % 40;
    const int bz = blk / 200;

    const int tid = threadIdx.x;
    const int x = bx * 32 + (tid & 31);
    const int y = by * 4 + ((tid >> 5) & 3);
    const int z = bz * 2 + (tid >> 7);

    const int idx = (z * S + y) * S + x;
    const float w0 = src[idx] * scale;
    const float w1 = src[idx + VOX] * scale;
    const float w2 = src[idx + 2 * VOX] * scale;

    const int f = brickf(x, y, z);
    float2 st = make_float2(w0, w1);
    __builtin_memcpy(dst + f, &st, 8);
    dst[f + 2] = w2;
}

// Mid step: brick -> brick, brick-linear thread order (r7-proven).
__global__ __launch_bounds__(THREADS) void svf_step(const float* __restrict__ src,
                                                    float* __restrict__ dst) {
    const int b   = blockIdx.x;
    const int blk = (b & (NXCD - 1)) * CHUNK + (b >> 3);
    const int m   = blk * THREADS + threadIdx.x;   // brick-linear voxel id

    const int lr = m & 3;
    const int t  = m >> 2;
    const int x  = t % S;
    const int u  = t / S;
    const int y  = (u % 80) * 2 + (lr & 1);
    const int z  = (u / 80) * 2 + (lr >> 1);

    const int f = m * 3;

    float4 own = ld4u(src + f);
    float n0, n1, n2;
    brick_gather(src, x, y, z, own.x, own.y, own.z, n0, n1, n2);

    float2 st = make_float2(n0, n1);
    __builtin_memcpy(dst + f, &st, 8);
    dst[f + 2] = n2;
}

// Final step: brick src -> planar dst + identity. Planar 32x4x2 tile mapping
// (copy-style) so planar stores are coalesced.
__global__ __launch_bounds__(THREADS) void svf_final(const float* __restrict__ src,
                                                     float* __restrict__ dst) {
    const int b   = blockIdx.x;
    const int blk = (b & (NXCD - 1)) * CHUNK + (b >> 3);
    const int bx = blk % 5;
    const int by = (blk / 5) % 40;
    const int bz = blk / 200;

    const int tid = threadIdx.x;
    const int x = bx * 32 + (tid & 31);
    const int y = by * 4 + ((tid >> 5) & 3);
    const int z = bz * 2 + (tid >> 7);

    const int f = brickf(x, y, z);
    float4 own = ld4u(src + f);
    float n0, n1, n2;
    brick_gather(src, x, y, z, own.x, own.y, own.z, n0, n1, n2);

    const int pidx = (z * S + y) * S + x;
    dst[pidx]           = idcoord(x) + n0;
    dst[pidx + VOX]     = idcoord(y) + n1;
    dst[pidx + 2 * VOX] = idcoord(z) + n2;
}

extern "C" void kernel_launch(void* const* d_in, const int* in_sizes, int n_in,
                              void* d_out, int out_size, void* d_ws, size_t ws_size,
                              hipStream_t stream) {
    // in[0] = identity_grid (recomputed analytically), in[1] = v
    const float* v = (const float*)d_in[1];
    float* out = (float*)d_out;
    float* ws  = (float*)d_ws;   // 3*160^3*4 = 49.15 MB used

    const float s = 1.0f / 65536.0f;  // 2^-16, exact

    // init: v (planar, scaled) -> out used as brick scratch
    svf_copy<<<BLOCKS, THREADS, 0, stream>>>(v, out, s);
    // steps 1..15: ping-pong; odd step -> ws, even step -> out.
    // step 15 lands in ws, so the final pass reads ws and writes out (planar).
    for (int k = 1; k <= 15; ++k) {
        if (k & 1)
            svf_step<<<BLOCKS, THREADS, 0, stream>>>(out, ws);
        else
            svf_step<<<BLOCKS, THREADS, 0, stream>>>(ws, out);
    }
    // step 16: ws (brick) -> d_out planar + identity
    svf_final<<<BLOCKS, THREADS, 0, stream>>>(ws, out);
}